// Round 11
// baseline (362.008 us; speedup 1.0000x reference)
//
#include <hip/hip_runtime.h>
#include <math.h>

// Problem constants (fixed by setup_inputs)
#define TOKENS 50176   // B*T*H*W = 2*8*56*56
#define NWIN   512     // total windows = B * 256
#define C_DIM  256

typedef __attribute__((ext_vector_type(8))) short short8;
typedef __attribute__((ext_vector_type(4))) short s16x4;
typedef __attribute__((ext_vector_type(4))) float f32x4;

// float -> bf16 with round-to-nearest-even
__device__ __forceinline__ unsigned short f2bf(float f) {
    unsigned int u = __builtin_bit_cast(unsigned int, f);
    u += 0x7fffu + ((u >> 16) & 1);
    return (unsigned short)(u >> 16);
}

// async global->LDS, 16B per lane (global_load_lds_dwordx4)
__device__ __forceinline__ void gll16(const void* g, void* l) {
    __builtin_amdgcn_global_load_lds(
        (const __attribute__((address_space(1))) unsigned int*)g,
        (__attribute__((address_space(3))) unsigned int*)l, 16, 0, 0);
}

// GELU, Phi-form A&S 7.1.26 (|eps|<=1.5e-7): gelu = v * phi(z),
// phi = (v<0) ? q : 1-q with q = p_half(t) * exp(-z^2); 0.5 folded into
// the poly coefficients. ~13 VALU ops, branch-free.
__device__ __forceinline__ float gelu_exact(float v) {
    float z  = v * 0.70710678118654752f;
    float az = fabsf(z);
    float t  = __builtin_amdgcn_rcpf(1.f + 0.3275911f * az);
    float ph = ((((0.5307027145f * t - 0.7265760135f) * t + 0.7107068705f) * t
                 - 0.142248368f) * t + 0.127414796f) * t;
    float q  = ph * __expf(-az * az);
    float phi = (v < 0.f) ? q : 1.f - q;
    return v * phi;
}

// Map a window-ordered token index u -> flat (b,t,h,w) index.
__device__ __forceinline__ int win_token_to_flat(int u) {
    int g = u / 98;
    int n = u - g * 98;
    int bb  = g >> 8;
    int rem = g & 255;
    int tb = rem >> 6, hb = (rem >> 3) & 7, wb = rem & 7;
    int dt = n / 49;
    int r2 = n - dt * 49;
    int dh = r2 / 7, dw = r2 - dh * 7;
    int t = tb * 2 + dt, h = hb * 7 + dh, w = wb * 7 + dw;
    int ts = (t + 1) & 7;
    int hs = h + 3; if (hs >= 56) hs -= 56;
    int wsx = w + 3; if (wsx >= 56) wsx -= 56;
    return ((bb * 8 + ts) * 56 + hs) * 56 + wsx;
}

// fused elementwise fp32 -> bf16 for all 4 weight matrices (one launch)
__global__ __launch_bounds__(256) void cvt_all_kernel(
        const float* __restrict__ s0, const float* __restrict__ s1,
        const float* __restrict__ s2, const float* __restrict__ s3,
        unsigned short* __restrict__ d0, unsigned short* __restrict__ d1,
        unsigned short* __restrict__ d2, unsigned short* __restrict__ d3) {
    int i = blockIdx.x * 256 + threadIdx.x;       // total 786432 exact
    if (i < 196608)      d0[i] = f2bf(s0[i]);                       // qkv_w
    else if (i < 262144) d1[i - 196608] = f2bf(s1[i - 196608]);     // proj_w
    else if (i < 524288) d2[i - 262144] = f2bf(s2[i - 262144]);     // fc1_w
    else                 d3[i - 524288] = f2bf(s3[i - 524288]);     // fc2_w
}

// Precompute combined rel-pos bias + shift mask tables:
// bm[cls 8][head 8][row 112][col 112] fp32.
__global__ __launch_bounds__(256) void bm_kernel(
        const float* __restrict__ rpe, float* __restrict__ bm) {
    int i = blockIdx.x * 256 + threadIdx.x;   // 8*8*112*112 = 802816 exact
    int c  = i % 112;
    int t1 = i / 112;
    int r  = t1 % 112;
    int t2 = t1 / 112;
    int head = t2 & 7;
    int cls  = t2 >> 3;
    float val;
    if (c >= 98) {
        val = -1e30f;
    } else if (r >= 98) {
        val = 0.f;
    } else {
        int dt = r / 49, rr = r - dt * 49, dh = rr / 7, dw = rr - dh * 7;
        int dt2 = c / 49, cc = c - dt2 * 49, dh2 = cc / 7, dw2 = cc - dh2 * 7;
        int rt  = (cls & 4) ? (dt  == 0 ? 1 : 2) : 0;
        int rh  = (cls & 2) ? (dh  <  4 ? 1 : 2) : 0;
        int rw  = (cls & 1) ? (dw  <  4 ? 1 : 2) : 0;
        int rt2 = (cls & 4) ? (dt2 == 0 ? 1 : 2) : 0;
        int rh2 = (cls & 2) ? (dh2 <  4 ? 1 : 2) : 0;
        int rw2 = (cls & 1) ? (dw2 <  4 ? 1 : 2) : 0;
        int reg1 = rt * 9 + rh * 3 + rw, reg2 = rt2 * 9 + rh2 * 3 + rw2;
        int idx = (dt - dt2 + 1) * 169 + (dh - dh2 + 6) * 13 + (dw - dw2 + 6);
        val = rpe[idx * 8 + head] + ((reg1 == reg2) ? 0.f : -100.f);
    }
    bm[i] = val;
}

// LayerNorm over C=256, one wave per token, bf16 output.
// GATHER: LN1 + roll + window partition fused (gather).
template<bool GATHER>
__global__ __launch_bounds__(256) void ln_kernel(
        const float* __restrict__ x, const float* __restrict__ w,
        const float* __restrict__ b, unsigned short* __restrict__ out) {
    int token = blockIdx.x * 4 + (threadIdx.x >> 6);
    int lane  = threadIdx.x & 63;
    size_t so = GATHER ? (size_t)win_token_to_flat(token) * C_DIM
                       : (size_t)token * C_DIM;
    const float* src = x + so;
    float v[4];
    float sum = 0.f;
#pragma unroll
    for (int j = 0; j < 4; ++j) { v[j] = src[lane + 64 * j]; sum += v[j]; }
#pragma unroll
    for (int o = 32; o > 0; o >>= 1) sum += __shfl_xor(sum, o, 64);
    float mu = sum * (1.f / 256.f);
    float var = 0.f;
#pragma unroll
    for (int j = 0; j < 4; ++j) { float d = v[j] - mu; var += d * d; }
#pragma unroll
    for (int o = 32; o > 0; o >>= 1) var += __shfl_xor(var, o, 64);
    float rstd = rsqrtf(var * (1.f / 256.f) + 1e-5f);
    unsigned short* dst = out + (size_t)token * C_DIM;
#pragma unroll
    for (int j = 0; j < 4; ++j) {
        int c = lane + 64 * j;
        dst[c] = f2bf((v[j] - mu) * rstd * w[c] + b[c]);
    }
}

// bf16 MFMA GEMM (qkv / fc1): C(MxN) = A(MxK) @ B(NxK)^T.
// r2 K-loop (dbuf LDS, one __syncthreads per step), XCD-bijective swizzle.
// EPI 0 (qkv): LDS-staged coalesced epilogue (bf16, *scale on Q cols).
// EPI 2 (fc1): DIRECT fragment-order stores (r11): the LDS round-trip's
//   64 ds_write_b16 + addressing made FC1 VALU-bound (VALUBusy 65%, r10);
//   adjacent j-stores cover contiguous 32B segments per row (cols 0-63 =
//   128B/row) which L2 write-combines, so staging buys little for bf16.
template<int EPI>
__global__ __launch_bounds__(256) void mfma_gemm(
        const unsigned short* __restrict__ A, const unsigned short* __restrict__ B,
        const float* __restrict__ bias,
        void* __restrict__ Cout, int M, int N, int K) {
    __shared__ __attribute__((aligned(16))) unsigned short smem[4][128 * 32]; // 32KB
#define ASMB(b) (smem[(b)])
#define BSMB(b) (smem[2 + (b)])
    int tid = threadIdx.x;
    int wave = tid >> 6, lane = tid & 63;

    int nwg = gridDim.x * gridDim.y;
    int bid = blockIdx.y * gridDim.x + blockIdx.x;
    int swz = (bid & 7) * (nwg >> 3) + (bid >> 3);
    int bx = swz % gridDim.x, by = swz / gridDim.x;

    int row0 = by * 128, col0 = bx * 128;
    int wr = (wave >> 1) * 64;
    int wc = (wave & 1) * 64;

    f32x4 acc[4][4] = {};

    int sr = tid >> 2;
    int sk = (tid & 3) * 8;
    const unsigned short* Ag0 = A + (size_t)(row0 + sr) * K + sk;
    const unsigned short* Ag1 = A + (size_t)(row0 + 64 + sr) * K + sk;
    const unsigned short* Bg0 = B + (size_t)(col0 + sr) * K + sk;
    const unsigned short* Bg1 = B + (size_t)(col0 + 64 + sr) * K + sk;
    int loff = tid * 8;

    int fm = lane & 15, fq = lane >> 4;
    int fks = fq * 8;

    gll16(Ag0, &ASMB(0)[loff]);
    gll16(Ag1, &ASMB(0)[loff + 2048]);
    gll16(Bg0, &BSMB(0)[loff]);
    gll16(Bg1, &BSMB(0)[loff + 2048]);

    int nk = K >> 5;
    for (int s = 0; s < nk; ++s) {
        int cur = s & 1;
        __syncthreads();
        if (s + 1 < nk) {
            int k0 = (s + 1) << 5;
            gll16(Ag0 + k0, &ASMB(cur ^ 1)[loff]);
            gll16(Ag1 + k0, &ASMB(cur ^ 1)[loff + 2048]);
            gll16(Bg0 + k0, &BSMB(cur ^ 1)[loff]);
            gll16(Bg1 + k0, &BSMB(cur ^ 1)[loff + 2048]);
        }
        short8 af[4], bfr[4];
#pragma unroll
        for (int t4 = 0; t4 < 4; ++t4) {
            af[t4]  = *(const short8*)&ASMB(cur)[(wr + t4 * 16 + fm) * 32 + fks];
            bfr[t4] = *(const short8*)&BSMB(cur)[(wc + t4 * 16 + fm) * 32 + fks];
        }
#pragma unroll
        for (int i = 0; i < 4; ++i)
#pragma unroll
            for (int j = 0; j < 4; ++j)
                acc[i][j] = __builtin_amdgcn_mfma_f32_16x16x32_bf16(
                    af[i], bfr[j], acc[i][j], 0, 0, 0);
    }

    int ccol0 = col0 + wc + fm;
    float bj[4];
#pragma unroll
    for (int j = 0; j < 4; ++j) bj[j] = bias[ccol0 + j * 16];

    if (EPI == 2) {
        // FC1: direct fragment-order stores, no LDS round-trip
        unsigned short* C = (unsigned short*)Cout;
        int crow0 = row0 + wr + fq * 4;
#pragma unroll
        for (int i = 0; i < 4; ++i)
#pragma unroll
            for (int v = 0; v < 4; ++v) {
                size_t base = (size_t)(crow0 + i * 16 + v) * N + ccol0;
#pragma unroll
                for (int j = 0; j < 4; ++j)
                    C[base + j * 16] = f2bf(gelu_exact(acc[i][j][v] + bj[j]));
            }
    } else {
        // qkv: LDS-staged coalesced epilogue
        __syncthreads();
        unsigned short* Ls = &smem[0][0];          // [128][128] ushort
        float mul = (col0 < 256) ? 0.17677669529663687f : 1.f;
#pragma unroll
        for (int i = 0; i < 4; ++i)
#pragma unroll
            for (int v = 0; v < 4; ++v) {
                int lr = wr + i * 16 + fq * 4 + v;
#pragma unroll
                for (int j = 0; j < 4; ++j)
                    Ls[lr * 128 + wc + j * 16 + fm] = f2bf((acc[i][j][v] + bj[j]) * mul);
            }
        __syncthreads();
        unsigned short* C = (unsigned short*)Cout;
#pragma unroll
        for (int p = 0; p < 8; ++p) {
            int lin = p * 2048 + tid * 8;
            int lr = lin >> 7, lc = lin & 127;
            *(short8*)(C + (size_t)(row0 + lr) * N + col0 + lc) =
                *(const short8*)&Ls[lin];
        }
    }
#undef ASMB
#undef BSMB
}

// ---------------------------------------------------------------------------
// FC2 GEMM, 64x128 tile: r2 K-loop + coalesced fp32 epilogue, grid 1568
// (6.1 blocks/CU). out = res + A@B^T + bias (fp32, in place).
// ---------------------------------------------------------------------------
__global__ __launch_bounds__(256) void fc2_kernel(
        const unsigned short* __restrict__ A, const unsigned short* __restrict__ B,
        const float* __restrict__ bias, const float* __restrict__ res,
        float* __restrict__ Cout, int M, int N, int K) {
    // ushort layout: A dbuf [2][64*32] @0 (2048 each); B dbuf [2][128*32] @4096
    __shared__ __attribute__((aligned(16))) unsigned short L[12288];
    int tid = threadIdx.x;
    int wave = tid >> 6, lane = tid & 63;
    int fm = lane & 15, fq = lane >> 4;

    int nwg = gridDim.x * gridDim.y;     // 1568
    int bid = blockIdx.y * gridDim.x + blockIdx.x;
    int swz = (bid & 7) * (nwg >> 3) + (bid >> 3);
    int bx = swz % gridDim.x, by = swz / gridDim.x;

    int row0 = by * 64, col0 = bx * 128;
    int wrow = (wave >> 1) * 32;
    int wcol = (wave & 1) * 64;

    f32x4 acc[2][4] = {};

    int sr = tid >> 2, sk = (tid & 3) * 8;
    const unsigned short* Ag  = A + (size_t)(row0 + sr) * K + sk;
    const unsigned short* Bg0 = B + (size_t)(col0 + sr) * K + sk;
    const unsigned short* Bg1 = B + (size_t)(col0 + 64 + sr) * K + sk;
    int loff = tid * 8;

    gll16(Ag,  &L[loff]);
    gll16(Bg0, &L[4096 + loff]);
    gll16(Bg1, &L[4096 + 2048 + loff]);

    int nk = K >> 5;                     // 32
    for (int s = 0; s < nk; ++s) {
        int cur = s & 1;
        __syncthreads();
        if (s + 1 < nk) {
            int k0 = (s + 1) << 5;
            gll16(Ag + k0,  &L[(cur ^ 1) * 2048 + loff]);
            gll16(Bg0 + k0, &L[4096 + (cur ^ 1) * 4096 + loff]);
            gll16(Bg1 + k0, &L[4096 + (cur ^ 1) * 4096 + 2048 + loff]);
        }
        short8 af[2], bfr[4];
#pragma unroll
        for (int i = 0; i < 2; ++i)
            af[i] = *(const short8*)&L[cur * 2048 + (wrow + i * 16 + fm) * 32 + fq * 8];
#pragma unroll
        for (int j = 0; j < 4; ++j)
            bfr[j] = *(const short8*)&L[4096 + cur * 4096 +
                                        (wcol + j * 16 + fm) * 32 + fq * 8];
#pragma unroll
        for (int i = 0; i < 2; ++i)
#pragma unroll
            for (int j = 0; j < 4; ++j)
                acc[i][j] = __builtin_amdgcn_mfma_f32_16x16x32_bf16(
                    af[i], bfr[j], acc[i][j], 0, 0, 0);
    }

    float bj[4];
#pragma unroll
    for (int j = 0; j < 4; ++j) bj[j] = bias[col0 + wcol + j * 16 + fm];

    __syncthreads();                     // K-loop LDS reads done; reuse L

    float* fs = (float*)L;               // [32][128] fp32 = 16KB
#pragma unroll
    for (int h = 0; h < 2; ++h) {
        if (h) __syncthreads();
        if ((wave >> 1) == h) {
#pragma unroll
            for (int i = 0; i < 2; ++i)
#pragma unroll
                for (int v = 0; v < 4; ++v) {
                    int lr = i * 16 + fq * 4 + v;
#pragma unroll
                    for (int j = 0; j < 4; ++j)
                        fs[lr * 128 + wcol + j * 16 + fm] = acc[i][j][v] + bj[j];
                }
        }
        __syncthreads();
        int tr = tid >> 3, c0 = (tid & 7) * 4;
        size_t gbase = (size_t)(row0 + h * 32 + tr) * N + col0;
        const float* rs = res + gbase;
        float* Cp = Cout + gbase;
        const float* ls = &fs[tr * 128];
#pragma unroll
        for (int q = 0; q < 4; ++q) {
            int c = c0 + q * 32;
            f32x4 r = *(const f32x4*)(rs + c);
            f32x4 a = *(const f32x4*)(ls + c);
            r.x += a.x; r.y += a.y; r.z += a.z; r.w += a.w;
            *(f32x4*)(Cp + c) = r;
        }
    }
}

// ---------------------------------------------------------------------------
// proj + window-reverse/roll scatter + residual + FUSED LayerNorm2.
// 32x256 tile, grid 1568; single-pass epilogue. Block owns full rows ->
// LN block-local. LDS 36KB.
// ---------------------------------------------------------------------------
__global__ __launch_bounds__(256) void proj_ln_kernel(
        const unsigned short* __restrict__ A,    // attnO (window order) bf16
        const unsigned short* __restrict__ B,    // wproj [256][256] bf16
        const float* __restrict__ bias,          // projb
        const float* __restrict__ res,           // x (flat order) fp32
        const float* __restrict__ n2w, const float* __restrict__ n2b,
        float* __restrict__ out,                 // x1 fp32 (flat)
        unsigned short* __restrict__ actA) {     // LN2(out) bf16 (flat)
    // ushort layout: A dbuf [2][32*32=1024] @0; B dbuf [2][256*32=8192] @2048
    __shared__ __attribute__((aligned(16))) unsigned short L[18432];  // 36KB
    int tid = threadIdx.x;
    int wave = tid >> 6, lane = tid & 63;
    int fm = lane & 15, fq = lane >> 4;

    int nwg = gridDim.x;                 // 1568
    int bid = blockIdx.x;
    int swz = (bid & 7) * (nwg >> 3) + (bid >> 3);
    int r0 = swz * 32;

    int wrow = (wave >> 1) * 16;         // 0 or 16
    int wcol = (wave & 1) * 128;         // 0 or 128

    f32x4 acc[8] = {};

    int sr = tid >> 2, sk = (tid & 3) * 8;
    const unsigned short* Ag = A + (size_t)(r0 + sr) * 256 + sk;
    const unsigned short* Bg = B + (size_t)sr * 256 + sk;

    if (tid < 128) gll16(Ag, &L[tid * 8]);
#pragma unroll
    for (int p = 0; p < 4; ++p)
        gll16(Bg + (size_t)p * 64 * 256, &L[2048 + p * 2048 + tid * 8]);

    for (int s = 0; s < 8; ++s) {
        int cur = s & 1;
        __syncthreads();
        if (s + 1 < 8) {
            int k0 = (s + 1) << 5;
            if (tid < 128) gll16(Ag + k0, &L[(cur ^ 1) * 1024 + tid * 8]);
#pragma unroll
            for (int p = 0; p < 4; ++p)
                gll16(Bg + (size_t)p * 64 * 256 + k0,
                      &L[2048 + (cur ^ 1) * 8192 + p * 2048 + tid * 8]);
        }
        short8 af = *(const short8*)&L[cur * 1024 + (wrow + fm) * 32 + fq * 8];
        short8 bfr[8];
#pragma unroll
        for (int j = 0; j < 8; ++j)
            bfr[j] = *(const short8*)&L[2048 + cur * 8192 +
                                        (wcol + j * 16 + fm) * 32 + fq * 8];
#pragma unroll
        for (int j = 0; j < 8; ++j)
            acc[j] = __builtin_amdgcn_mfma_f32_16x16x32_bf16(
                af, bfr[j], acc[j], 0, 0, 0);
    }

    float bj[8];
#pragma unroll
    for (int j = 0; j < 8; ++j) bj[j] = bias[wcol + j * 16 + fm];

    __syncthreads();                     // K-loop LDS reads done; reuse L

    float* fs   = (float*)L;             // [32][260] fp32 (stride-pad 4)
    float* redu = (float*)&L[16640];     // [32][8][2] fp32 (2KB)

#pragma unroll
    for (int v = 0; v < 4; ++v) {
        int lr = wrow + fq * 4 + v;
#pragma unroll
        for (int j = 0; j < 8; ++j)
            fs[lr * 260 + wcol + j * 16 + fm] = acc[j][v] + bj[j];
    }
    __syncthreads();                     // fs ready
    int tr = tid >> 3;                   // row 0..31
    int c0 = (tid & 7) * 4;              // interleaved float4 chunks
    int flat = win_token_to_flat(r0 + tr);
    size_t gb = (size_t)flat * 256;
    float vals[32];
    float s1 = 0.f, s2 = 0.f;
#pragma unroll
    for (int q = 0; q < 8; ++q) {
        int c = c0 + q * 32;
        f32x4 rr = *(const f32x4*)(res + gb + c);
        f32x4 aa = *(const f32x4*)&fs[tr * 260 + c];
        f32x4 o;
        o.x = rr.x + aa.x; o.y = rr.y + aa.y;
        o.z = rr.z + aa.z; o.w = rr.w + aa.w;
        *(f32x4*)(out + gb + c) = o;
        vals[q * 4 + 0] = o.x; vals[q * 4 + 1] = o.y;
        vals[q * 4 + 2] = o.z; vals[q * 4 + 3] = o.w;
        s1 += o.x + o.y + o.z + o.w;
        s2 += o.x * o.x + o.y * o.y + o.z * o.z + o.w * o.w;
    }
    redu[(tr * 8 + (tid & 7)) * 2 + 0] = s1;
    redu[(tr * 8 + (tid & 7)) * 2 + 1] = s2;
    __syncthreads();                     // redu ready
    float S = 0.f, Q = 0.f;
#pragma unroll
    for (int g2 = 0; g2 < 8; ++g2) {
        S += redu[(tr * 8 + g2) * 2 + 0];
        Q += redu[(tr * 8 + g2) * 2 + 1];
    }
    float mu = S * (1.f / 256.f);
    float var = Q * (1.f / 256.f) - mu * mu;
    float rstd = rsqrtf(var + 1e-5f);
#pragma unroll
    for (int q = 0; q < 8; ++q) {
        int c = c0 + q * 32;
        f32x4 w4 = *(const f32x4*)(n2w + c);
        f32x4 b4 = *(const f32x4*)(n2b + c);
        s16x4 pk;
        pk[0] = (short)f2bf((vals[q * 4 + 0] - mu) * rstd * w4.x + b4.x);
        pk[1] = (short)f2bf((vals[q * 4 + 1] - mu) * rstd * w4.y + b4.y);
        pk[2] = (short)f2bf((vals[q * 4 + 2] - mu) * rstd * w4.z + b4.z);
        pk[3] = (short)f2bf((vals[q * 4 + 3] - mu) * rstd * w4.w + b4.w);
        *(s16x4*)(actA + gb + c) = pk;
    }
}

// MFMA windowed attention: one block per (window, head), 4 waves.
__global__ __launch_bounds__(256) void attn_mfma_kernel(
        const unsigned short* __restrict__ qkv, const float* __restrict__ bm,
        unsigned short* __restrict__ out) {
    __shared__ __attribute__((aligned(16))) unsigned short Vt[32][136];
    __shared__ __attribute__((aligned(16))) unsigned short Pw[4][16][136];
    int blk = blockIdx.x;
    int g = blk >> 3, head = blk & 7;
    int tid = threadIdx.x, wave = tid >> 6, lane = tid & 63;

    for (int i = tid; i < 32 * 30; i += 256) {
        int d = i / 30, c = 98 + (i - d * 30);
        Vt[d][c] = 0;
    }
    const unsigned short* vbase = qkv + (size_t)g * 98 * 768 + 512 + head * 32;
    for (int i = tid; i < 98 * 16; i += 256) {
        int n = i >> 4, dp = i & 15;
        unsigned int val = *(const unsigned int*)(vbase + (size_t)n * 768 + dp * 2);
        Vt[dp * 2][n]     = (unsigned short)val;
        Vt[dp * 2 + 1][n] = (unsigned short)(val >> 16);
    }
    {
        int m = lane >> 2, c = 112 + (lane & 3) * 4;
        *(unsigned long long*)&Pw[wave][m][c] = 0ULL;
    }
    __syncthreads();

    const unsigned short* qbase = qkv + (size_t)g * 98 * 768 + head * 32;
    const unsigned short* kbase = qbase + 256;
    int rem = g & 255;
    int cls = (((rem >> 6) == 3) << 2) | (((((rem >> 3) & 7)) == 7) << 1) | ((rem & 7) == 7);
    const float* bmh = bm + (size_t)(cls * 8 + head) * 112 * 112;

    int fm = lane & 15, fq = lane >> 4;
    int fk = fq * 8;
    unsigned short* obase = out + (size_t)g * 98 * 256 + head * 32;

    for (int s = wave; s < 7; s += 4) {
        int m0 = s * 16;
        int arow = m0 + fm; if (arow > 97) arow = 97;
        short8 af = *(const short8*)(qbase + (size_t)arow * 768 + fk);
        f32x4 S[7];
        f32x4 z = {0.f, 0.f, 0.f, 0.f};
#pragma unroll
        for (int j = 0; j < 7; ++j) {
            int krow = j * 16 + fm; if (krow > 97) krow = 97;
            short8 kf = *(const short8*)(kbase + (size_t)krow * 768 + fk);
            S[j] = __builtin_amdgcn_mfma_f32_16x16x32_bf16(af, kf, z, 0, 0, 0);
        }
        const float* bmrow = bmh + (m0 + fq * 4) * 112 + fm;
#pragma unroll
        for (int j = 0; j < 7; ++j)
#pragma unroll
            for (int v = 0; v < 4; ++v)
                S[j][v] += bmrow[v * 112 + j * 16];
        float inv[4];
#pragma unroll
        for (int v = 0; v < 4; ++v) {
            float m_ = S[0][v];
#pragma unroll
            for (int j = 1; j < 7; ++j) m_ = fmaxf(m_, S[j][v]);
#pragma unroll
            for (int o = 1; o < 16; o <<= 1) m_ = fmaxf(m_, __shfl_xor(m_, o, 64));
            float t = 0.f;
#pragma unroll
            for (int j = 0; j < 7; ++j) { S[j][v] = __expf(S[j][v] - m_); t += S[j][v]; }
#pragma unroll
            for (int o = 1; o < 16; o <<= 1) t += __shfl_xor(t, o, 64);
            inv[v] = 1.f / t;
        }
#pragma unroll
        for (int j = 0; j < 7; ++j)
#pragma unroll
            for (int v = 0; v < 4; ++v)
                Pw[wave][fq * 4 + v][j * 16 + fm] = f2bf(S[j][v]);
        f32x4 O0 = {0.f, 0.f, 0.f, 0.f}, O1 = {0.f, 0.f, 0.f, 0.f};
#pragma unroll
        for (int ks = 0; ks < 4; ++ks) {
            short8 pf = *(const short8*)&Pw[wave][fm][ks * 32 + fk];
            short8 v0 = *(const short8*)&Vt[fm][ks * 32 + fk];
            short8 v1 = *(const short8*)&Vt[16 + fm][ks * 32 + fk];
            O0 = __builtin_amdgcn_mfma_f32_16x16x32_bf16(pf, v0, O0, 0, 0, 0);
            O1 = __builtin_amdgcn_mfma_f32_16x16x32_bf16(pf, v1, O1, 0, 0, 0);
        }
#pragma unroll
        for (int v = 0; v < 4; ++v) {
            int row = m0 + fq * 4 + v;
            if (row < 98) {
                obase[(size_t)row * 256 + fm]      = f2bf(O0[v] * inv[v]);
                obase[(size_t)row * 256 + 16 + fm] = f2bf(O1[v] * inv[v]);
            }
        }
    }
}

extern "C" void kernel_launch(void* const* d_in, const int* in_sizes, int n_in,
                              void* d_out, int out_size, void* d_ws, size_t ws_size,
                              hipStream_t stream) {
    const float* x     = (const float*)d_in[0];
    const float* n1w   = (const float*)d_in[1];
    const float* n1b   = (const float*)d_in[2];
    const float* qkvw  = (const float*)d_in[3];
    const float* qkvb  = (const float*)d_in[4];
    const float* projw = (const float*)d_in[5];
    const float* projb = (const float*)d_in[6];
    const float* rpe   = (const float*)d_in[7];
    const float* n2w   = (const float*)d_in[8];
    const float* n2b   = (const float*)d_in[9];
    const float* fc1w  = (const float*)d_in[10];
    const float* fc1b  = (const float*)d_in[11];
    const float* fc2w  = (const float*)d_in[12];
    const float* fc2b  = (const float*)d_in[13];
    float* out = (float*)d_out;

    // workspace layout
    unsigned short* wqkv  = (unsigned short*)d_ws;            // 768*256 bf16
    unsigned short* wproj = wqkv + 768 * 256;                 // 256*256
    unsigned short* wfc1  = wproj + 256 * 256;                // 1024*256
    unsigned short* wfc2  = wfc1 + 1024 * 256;                // 256*1024
    float* bm = (float*)(wfc2 + 256 * 1024);                  // 8*8*112*112 fp32
    unsigned short* actA  = (unsigned short*)(bm + 8 * 8 * 112 * 112); // TOKENS*256 bf16
    unsigned short* attnO = actA + (size_t)TOKENS * 256;      // TOKENS*256 bf16
    unsigned short* qkv_bf = attnO + (size_t)TOKENS * 256;    // TOKENS*768 bf16
    unsigned short* fc1o = qkv_bf;                            // TOKENS*1024 bf16 (aliases dead qkv)

    // 0. bias/mask tables + weight casts (single fused cast launch)
    bm_kernel<<<8 * 8 * 112 * 112 / 256, 256, 0, stream>>>(rpe, bm);
    cvt_all_kernel<<<786432 / 256, 256, 0, stream>>>(
        qkvw, projw, fc1w, fc2w, wqkv, wproj, wfc1, wfc2);

    // 1. LN1 + roll + window partition (gather), bf16 out
    ln_kernel<true><<<TOKENS / 4, 256, 0, stream>>>(x, n1w, n1b, actA);
    // 2. QKV projection -> bf16, Q pre-scaled
    mfma_gemm<0><<<dim3(768 / 128, TOKENS / 128), 256, 0, stream>>>(
        actA, wqkv, qkvb, qkv_bf, TOKENS, 768, 256);
    // 3. MFMA windowed attention -> bf16
    attn_mfma_kernel<<<NWIN * 8, 256, 0, stream>>>(qkv_bf, bm, attnO);
    // 4. proj + scatter + residual + FUSED LN2 -> out (fp32) + actA (bf16)
    proj_ln_kernel<<<TOKENS / 32, 256, 0, stream>>>(
        attnO, wproj, projb, x, n2w, n2b, out, actA);
    // 5. FC1 + GELU -> bf16, direct stores (aliases dead qkv buffer)
    mfma_gemm<2><<<dim3(1024 / 128, TOKENS / 128), 256, 0, stream>>>(
        actA, wfc1, fc1b, fc1o, TOKENS, 1024, 256);
    // 6. FC2 + residual (in place on d_out), 64x128 tiles
    fc2_kernel<<<dim3(256 / 128, TOKENS / 64), 256, 0, stream>>>(
        fc1o, wfc2, fc2b, out, out, TOKENS, 256, 1024);
}

// Round 12
// 360.370 us; speedup vs baseline: 1.0045x; 1.0045x over previous
//
#include <hip/hip_runtime.h>
#include <math.h>

// Problem constants (fixed by setup_inputs)
#define TOKENS 50176   // B*T*H*W = 2*8*56*56
#define NWIN   512     // total windows = B * 256
#define C_DIM  256

typedef __attribute__((ext_vector_type(8))) short short8;
typedef __attribute__((ext_vector_type(4))) short s16x4;
typedef __attribute__((ext_vector_type(4))) float f32x4;

// float -> bf16 with round-to-nearest-even
__device__ __forceinline__ unsigned short f2bf(float f) {
    unsigned int u = __builtin_bit_cast(unsigned int, f);
    u += 0x7fffu + ((u >> 16) & 1);
    return (unsigned short)(u >> 16);
}

// async global->LDS, 16B per lane (global_load_lds_dwordx4)
__device__ __forceinline__ void gll16(const void* g, void* l) {
    __builtin_amdgcn_global_load_lds(
        (const __attribute__((address_space(1))) unsigned int*)g,
        (__attribute__((address_space(3))) unsigned int*)l, 16, 0, 0);
}

// GELU, Phi-form A&S 7.1.26 (|eps|<=1.5e-7): gelu = v * phi(z),
// phi = (v<0) ? q : 1-q with q = p_half(t) * exp(-z^2); 0.5 folded into
// the poly coefficients. ~13 VALU ops, branch-free.
__device__ __forceinline__ float gelu_exact(float v) {
    float z  = v * 0.70710678118654752f;
    float az = fabsf(z);
    float t  = __builtin_amdgcn_rcpf(1.f + 0.3275911f * az);
    float ph = ((((0.5307027145f * t - 0.7265760135f) * t + 0.7107068705f) * t
                 - 0.142248368f) * t + 0.127414796f) * t;
    float q  = ph * __expf(-az * az);
    float phi = (v < 0.f) ? q : 1.f - q;
    return v * phi;
}

// Map a window-ordered token index u -> flat (b,t,h,w) index.
__device__ __forceinline__ int win_token_to_flat(int u) {
    int g = u / 98;
    int n = u - g * 98;
    int bb  = g >> 8;
    int rem = g & 255;
    int tb = rem >> 6, hb = (rem >> 3) & 7, wb = rem & 7;
    int dt = n / 49;
    int r2 = n - dt * 49;
    int dh = r2 / 7, dw = r2 - dh * 7;
    int t = tb * 2 + dt, h = hb * 7 + dh, w = wb * 7 + dw;
    int ts = (t + 1) & 7;
    int hs = h + 3; if (hs >= 56) hs -= 56;
    int wsx = w + 3; if (wsx >= 56) wsx -= 56;
    return ((bb * 8 + ts) * 56 + hs) * 56 + wsx;
}

// fused elementwise fp32 -> bf16 for all 4 weight matrices (one launch)
__global__ __launch_bounds__(256) void cvt_all_kernel(
        const float* __restrict__ s0, const float* __restrict__ s1,
        const float* __restrict__ s2, const float* __restrict__ s3,
        unsigned short* __restrict__ d0, unsigned short* __restrict__ d1,
        unsigned short* __restrict__ d2, unsigned short* __restrict__ d3) {
    int i = blockIdx.x * 256 + threadIdx.x;       // total 786432 exact
    if (i < 196608)      d0[i] = f2bf(s0[i]);                       // qkv_w
    else if (i < 262144) d1[i - 196608] = f2bf(s1[i - 196608]);     // proj_w
    else if (i < 524288) d2[i - 262144] = f2bf(s2[i - 262144]);     // fc1_w
    else                 d3[i - 524288] = f2bf(s3[i - 524288]);     // fc2_w
}

// Precompute combined rel-pos bias + shift mask tables:
// bm[cls 8][head 8][row 112][col 112] fp32.
__global__ __launch_bounds__(256) void bm_kernel(
        const float* __restrict__ rpe, float* __restrict__ bm) {
    int i = blockIdx.x * 256 + threadIdx.x;   // 8*8*112*112 = 802816 exact
    int c  = i % 112;
    int t1 = i / 112;
    int r  = t1 % 112;
    int t2 = t1 / 112;
    int head = t2 & 7;
    int cls  = t2 >> 3;
    float val;
    if (c >= 98) {
        val = -1e30f;
    } else if (r >= 98) {
        val = 0.f;
    } else {
        int dt = r / 49, rr = r - dt * 49, dh = rr / 7, dw = rr - dh * 7;
        int dt2 = c / 49, cc = c - dt2 * 49, dh2 = cc / 7, dw2 = cc - dh2 * 7;
        int rt  = (cls & 4) ? (dt  == 0 ? 1 : 2) : 0;
        int rh  = (cls & 2) ? (dh  <  4 ? 1 : 2) : 0;
        int rw  = (cls & 1) ? (dw  <  4 ? 1 : 2) : 0;
        int rt2 = (cls & 4) ? (dt2 == 0 ? 1 : 2) : 0;
        int rh2 = (cls & 2) ? (dh2 <  4 ? 1 : 2) : 0;
        int rw2 = (cls & 1) ? (dw2 <  4 ? 1 : 2) : 0;
        int reg1 = rt * 9 + rh * 3 + rw, reg2 = rt2 * 9 + rh2 * 3 + rw2;
        int idx = (dt - dt2 + 1) * 169 + (dh - dh2 + 6) * 13 + (dw - dw2 + 6);
        val = rpe[idx * 8 + head] + ((reg1 == reg2) ? 0.f : -100.f);
    }
    bm[i] = val;
}

// LayerNorm over C=256, one wave per token, bf16 output.
// GATHER: LN1 + roll + window partition fused (gather).
template<bool GATHER>
__global__ __launch_bounds__(256) void ln_kernel(
        const float* __restrict__ x, const float* __restrict__ w,
        const float* __restrict__ b, unsigned short* __restrict__ out) {
    int token = blockIdx.x * 4 + (threadIdx.x >> 6);
    int lane  = threadIdx.x & 63;
    size_t so = GATHER ? (size_t)win_token_to_flat(token) * C_DIM
                       : (size_t)token * C_DIM;
    const float* src = x + so;
    float v[4];
    float sum = 0.f;
#pragma unroll
    for (int j = 0; j < 4; ++j) { v[j] = src[lane + 64 * j]; sum += v[j]; }
#pragma unroll
    for (int o = 32; o > 0; o >>= 1) sum += __shfl_xor(sum, o, 64);
    float mu = sum * (1.f / 256.f);
    float var = 0.f;
#pragma unroll
    for (int j = 0; j < 4; ++j) { float d = v[j] - mu; var += d * d; }
#pragma unroll
    for (int o = 32; o > 0; o >>= 1) var += __shfl_xor(var, o, 64);
    float rstd = rsqrtf(var * (1.f / 256.f) + 1e-5f);
    unsigned short* dst = out + (size_t)token * C_DIM;
#pragma unroll
    for (int j = 0; j < 4; ++j) {
        int c = lane + 64 * j;
        dst[c] = f2bf((v[j] - mu) * rstd * w[c] + b[c]);
    }
}

// bf16 MFMA GEMM (qkv / fc1): C(MxN) = A(MxK) @ B(NxK)^T.
// r2 K-loop (dbuf LDS, one __syncthreads per step), XCD-bijective swizzle.
// EPI 0 (qkv): LDS-staged coalesced epilogue (bf16, *scale on Q cols).
// EPI 2 (fc1): direct fragment-order stores (r11: LDS round-trip made FC1
//   VALU-bound; adjacent j-stores L2-write-combine fine for bf16).
template<int EPI>
__global__ __launch_bounds__(256) void mfma_gemm(
        const unsigned short* __restrict__ A, const unsigned short* __restrict__ B,
        const float* __restrict__ bias,
        void* __restrict__ Cout, int M, int N, int K) {
    __shared__ __attribute__((aligned(16))) unsigned short smem[4][128 * 32]; // 32KB
#define ASMB(b) (smem[(b)])
#define BSMB(b) (smem[2 + (b)])
    int tid = threadIdx.x;
    int wave = tid >> 6, lane = tid & 63;

    int nwg = gridDim.x * gridDim.y;
    int bid = blockIdx.y * gridDim.x + blockIdx.x;
    int swz = (bid & 7) * (nwg >> 3) + (bid >> 3);
    int bx = swz % gridDim.x, by = swz / gridDim.x;

    int row0 = by * 128, col0 = bx * 128;
    int wr = (wave >> 1) * 64;
    int wc = (wave & 1) * 64;

    f32x4 acc[4][4] = {};

    int sr = tid >> 2;
    int sk = (tid & 3) * 8;
    const unsigned short* Ag0 = A + (size_t)(row0 + sr) * K + sk;
    const unsigned short* Ag1 = A + (size_t)(row0 + 64 + sr) * K + sk;
    const unsigned short* Bg0 = B + (size_t)(col0 + sr) * K + sk;
    const unsigned short* Bg1 = B + (size_t)(col0 + 64 + sr) * K + sk;
    int loff = tid * 8;

    int fm = lane & 15, fq = lane >> 4;
    int fks = fq * 8;

    gll16(Ag0, &ASMB(0)[loff]);
    gll16(Ag1, &ASMB(0)[loff + 2048]);
    gll16(Bg0, &BSMB(0)[loff]);
    gll16(Bg1, &BSMB(0)[loff + 2048]);

    int nk = K >> 5;
    for (int s = 0; s < nk; ++s) {
        int cur = s & 1;
        __syncthreads();
        if (s + 1 < nk) {
            int k0 = (s + 1) << 5;
            gll16(Ag0 + k0, &ASMB(cur ^ 1)[loff]);
            gll16(Ag1 + k0, &ASMB(cur ^ 1)[loff + 2048]);
            gll16(Bg0 + k0, &BSMB(cur ^ 1)[loff]);
            gll16(Bg1 + k0, &BSMB(cur ^ 1)[loff + 2048]);
        }
        short8 af[4], bfr[4];
#pragma unroll
        for (int t4 = 0; t4 < 4; ++t4) {
            af[t4]  = *(const short8*)&ASMB(cur)[(wr + t4 * 16 + fm) * 32 + fks];
            bfr[t4] = *(const short8*)&BSMB(cur)[(wc + t4 * 16 + fm) * 32 + fks];
        }
#pragma unroll
        for (int i = 0; i < 4; ++i)
#pragma unroll
            for (int j = 0; j < 4; ++j)
                acc[i][j] = __builtin_amdgcn_mfma_f32_16x16x32_bf16(
                    af[i], bfr[j], acc[i][j], 0, 0, 0);
    }

    int ccol0 = col0 + wc + fm;
    float bj[4];
#pragma unroll
    for (int j = 0; j < 4; ++j) bj[j] = bias[ccol0 + j * 16];

    if (EPI == 2) {
        // FC1: direct fragment-order stores, no LDS round-trip
        unsigned short* C = (unsigned short*)Cout;
        int crow0 = row0 + wr + fq * 4;
#pragma unroll
        for (int i = 0; i < 4; ++i)
#pragma unroll
            for (int v = 0; v < 4; ++v) {
                size_t base = (size_t)(crow0 + i * 16 + v) * N + ccol0;
#pragma unroll
                for (int j = 0; j < 4; ++j)
                    C[base + j * 16] = f2bf(gelu_exact(acc[i][j][v] + bj[j]));
            }
    } else {
        // qkv: LDS-staged coalesced epilogue
        __syncthreads();
        unsigned short* Ls = &smem[0][0];          // [128][128] ushort
        float mul = (col0 < 256) ? 0.17677669529663687f : 1.f;
#pragma unroll
        for (int i = 0; i < 4; ++i)
#pragma unroll
            for (int v = 0; v < 4; ++v) {
                int lr = wr + i * 16 + fq * 4 + v;
#pragma unroll
                for (int j = 0; j < 4; ++j)
                    Ls[lr * 128 + wc + j * 16 + fm] = f2bf((acc[i][j][v] + bj[j]) * mul);
            }
        __syncthreads();
        unsigned short* C = (unsigned short*)Cout;
#pragma unroll
        for (int p = 0; p < 8; ++p) {
            int lin = p * 2048 + tid * 8;
            int lr = lin >> 7, lc = lin & 127;
            *(short8*)(C + (size_t)(row0 + lr) * N + col0 + lc) =
                *(const short8*)&Ls[lin];
        }
    }
#undef ASMB
#undef BSMB
}

// ---------------------------------------------------------------------------
// FC2 GEMM, 64x128 tile, r12: 2 K-steps per barrier, 4 LDS buffers (48KB).
// The r11 counters pinned fc2's 59.5us at one loaded-memory-latency per
// K-step: the __syncthreads vmcnt(0) drain waits for loads issued only one
// step (~300cy compute) earlier. With 4 buffers, loads drained at barrier i
// were issued at iteration i-1 = TWO K-steps (~600-800cy) earlier, and the
// barrier count halves (32 -> 16). Costs blocks/CU (6 -> 3): this round
// pits prefetch-depth against TLP on the same kernel.
// WAR audit: iter i reads bufs (2i)&3,(2i+1)&3; issues steps 2i+2,2i+3 into
// bufs last read at iter i-1, sealed by this iteration's barrier.
// out = res + A@B^T + bias (fp32, in place: res == out).
// ---------------------------------------------------------------------------
__global__ __launch_bounds__(256) void fc2_kernel(
        const unsigned short* __restrict__ A, const unsigned short* __restrict__ B,
        const float* __restrict__ bias, const float* __restrict__ res,
        float* __restrict__ Cout, int M, int N, int K) {
    // ushort layout: A bufs [4][2048] @0 (4KB each); B bufs [4][4096] @8192
    __shared__ __attribute__((aligned(16))) unsigned short L[24576];  // 48KB
    int tid = threadIdx.x;
    int wave = tid >> 6, lane = tid & 63;
    int fm = lane & 15, fq = lane >> 4;

    int nwg = gridDim.x * gridDim.y;     // 1568
    int bid = blockIdx.y * gridDim.x + blockIdx.x;
    int swz = (bid & 7) * (nwg >> 3) + (bid >> 3);
    int bx = swz % gridDim.x, by = swz / gridDim.x;

    int row0 = by * 64, col0 = bx * 128;
    int wrow = (wave >> 1) * 32;
    int wcol = (wave & 1) * 64;

    f32x4 acc[2][4] = {};

    int sr = tid >> 2, sk = (tid & 3) * 8;
    const unsigned short* Ag  = A + (size_t)(row0 + sr) * K + sk;
    const unsigned short* Bg0 = B + (size_t)(col0 + sr) * K + sk;
    const unsigned short* Bg1 = B + (size_t)(col0 + 64 + sr) * K + sk;
    int loff = tid * 8;

    // stage K-step s into buf s&3
#define STAGE(s)  do { int _k = (s) << 5; int _b = (s) & 3;                    \
        gll16(Ag  + _k, &L[_b * 2048 + loff]);                                 \
        gll16(Bg0 + _k, &L[8192 + _b * 4096 + loff]);                          \
        gll16(Bg1 + _k, &L[8192 + _b * 4096 + 2048 + loff]); } while (0)

    // prologue: steps 0,1 in flight
    STAGE(0);
    STAGE(1);

    int nk = K >> 5;                     // 32 (even)
    for (int i = 0; i < nk; i += 2) {
        __syncthreads();                 // steps i,i+1 staged; bufs (i+2)&3,(i+3)&3 sealed
        if (i + 2 < nk) { STAGE(i + 2); STAGE(i + 3); }
#pragma unroll
        for (int u = 0; u < 2; ++u) {
            int b = (i + u) & 3;
            short8 af[2], bfr[4];
#pragma unroll
            for (int r = 0; r < 2; ++r)
                af[r] = *(const short8*)&L[b * 2048 + (wrow + r * 16 + fm) * 32 + fq * 8];
#pragma unroll
            for (int j = 0; j < 4; ++j)
                bfr[j] = *(const short8*)&L[8192 + b * 4096 +
                                            (wcol + j * 16 + fm) * 32 + fq * 8];
#pragma unroll
            for (int r = 0; r < 2; ++r)
#pragma unroll
                for (int j = 0; j < 4; ++j)
                    acc[r][j] = __builtin_amdgcn_mfma_f32_16x16x32_bf16(
                        af[r], bfr[j], acc[r][j], 0, 0, 0);
        }
    }
#undef STAGE

    float bj[4];
#pragma unroll
    for (int j = 0; j < 4; ++j) bj[j] = bias[col0 + wcol + j * 16 + fm];

    __syncthreads();                     // K-loop LDS reads done; reuse L

    float* fs = (float*)L;               // [32][128] fp32 = 16KB
#pragma unroll
    for (int h = 0; h < 2; ++h) {
        if (h) __syncthreads();
        if ((wave >> 1) == h) {
#pragma unroll
            for (int r = 0; r < 2; ++r)
#pragma unroll
                for (int v = 0; v < 4; ++v) {
                    int lr = r * 16 + fq * 4 + v;
#pragma unroll
                    for (int j = 0; j < 4; ++j)
                        fs[lr * 128 + wcol + j * 16 + fm] = acc[r][j][v] + bj[j];
                }
        }
        __syncthreads();
        int tr = tid >> 3, c0 = (tid & 7) * 4;
        size_t gbase = (size_t)(row0 + h * 32 + tr) * N + col0;
        const float* rs = res + gbase;
        float* Cp = Cout + gbase;
        const float* ls = &fs[tr * 128];
#pragma unroll
        for (int q = 0; q < 4; ++q) {
            int c = c0 + q * 32;
            f32x4 r = *(const f32x4*)(rs + c);
            f32x4 a = *(const f32x4*)(ls + c);
            r.x += a.x; r.y += a.y; r.z += a.z; r.w += a.w;
            *(f32x4*)(Cp + c) = r;
        }
    }
}

// ---------------------------------------------------------------------------
// proj + window-reverse/roll scatter + residual + FUSED LayerNorm2.
// 32x256 tile, grid 1568; single-pass epilogue. Block owns full rows ->
// LN block-local. LDS 36KB.
// ---------------------------------------------------------------------------
__global__ __launch_bounds__(256) void proj_ln_kernel(
        const unsigned short* __restrict__ A,    // attnO (window order) bf16
        const unsigned short* __restrict__ B,    // wproj [256][256] bf16
        const float* __restrict__ bias,          // projb
        const float* __restrict__ res,           // x (flat order) fp32
        const float* __restrict__ n2w, const float* __restrict__ n2b,
        float* __restrict__ out,                 // x1 fp32 (flat)
        unsigned short* __restrict__ actA) {     // LN2(out) bf16 (flat)
    // ushort layout: A dbuf [2][32*32=1024] @0; B dbuf [2][256*32=8192] @2048
    __shared__ __attribute__((aligned(16))) unsigned short L[18432];  // 36KB
    int tid = threadIdx.x;
    int wave = tid >> 6, lane = tid & 63;
    int fm = lane & 15, fq = lane >> 4;

    int nwg = gridDim.x;                 // 1568
    int bid = blockIdx.x;
    int swz = (bid & 7) * (nwg >> 3) + (bid >> 3);
    int r0 = swz * 32;

    int wrow = (wave >> 1) * 16;         // 0 or 16
    int wcol = (wave & 1) * 128;         // 0 or 128

    f32x4 acc[8] = {};

    int sr = tid >> 2, sk = (tid & 3) * 8;
    const unsigned short* Ag = A + (size_t)(r0 + sr) * 256 + sk;
    const unsigned short* Bg = B + (size_t)sr * 256 + sk;

    if (tid < 128) gll16(Ag, &L[tid * 8]);
#pragma unroll
    for (int p = 0; p < 4; ++p)
        gll16(Bg + (size_t)p * 64 * 256, &L[2048 + p * 2048 + tid * 8]);

    for (int s = 0; s < 8; ++s) {
        int cur = s & 1;
        __syncthreads();
        if (s + 1 < 8) {
            int k0 = (s + 1) << 5;
            if (tid < 128) gll16(Ag + k0, &L[(cur ^ 1) * 1024 + tid * 8]);
#pragma unroll
            for (int p = 0; p < 4; ++p)
                gll16(Bg + (size_t)p * 64 * 256 + k0,
                      &L[2048 + (cur ^ 1) * 8192 + p * 2048 + tid * 8]);
        }
        short8 af = *(const short8*)&L[cur * 1024 + (wrow + fm) * 32 + fq * 8];
        short8 bfr[8];
#pragma unroll
        for (int j = 0; j < 8; ++j)
            bfr[j] = *(const short8*)&L[2048 + cur * 8192 +
                                        (wcol + j * 16 + fm) * 32 + fq * 8];
#pragma unroll
        for (int j = 0; j < 8; ++j)
            acc[j] = __builtin_amdgcn_mfma_f32_16x16x32_bf16(
                af, bfr[j], acc[j], 0, 0, 0);
    }

    float bj[8];
#pragma unroll
    for (int j = 0; j < 8; ++j) bj[j] = bias[wcol + j * 16 + fm];

    __syncthreads();                     // K-loop LDS reads done; reuse L

    float* fs   = (float*)L;             // [32][260] fp32 (stride-pad 4)
    float* redu = (float*)&L[16640];     // [32][8][2] fp32 (2KB)

#pragma unroll
    for (int v = 0; v < 4; ++v) {
        int lr = wrow + fq * 4 + v;
#pragma unroll
        for (int j = 0; j < 8; ++j)
            fs[lr * 260 + wcol + j * 16 + fm] = acc[j][v] + bj[j];
    }
    __syncthreads();                     // fs ready
    int tr = tid >> 3;                   // row 0..31
    int c0 = (tid & 7) * 4;              // interleaved float4 chunks
    int flat = win_token_to_flat(r0 + tr);
    size_t gb = (size_t)flat * 256;
    float vals[32];
    float s1 = 0.f, s2 = 0.f;
#pragma unroll
    for (int q = 0; q < 8; ++q) {
        int c = c0 + q * 32;
        f32x4 rr = *(const f32x4*)(res + gb + c);
        f32x4 aa = *(const f32x4*)&fs[tr * 260 + c];
        f32x4 o;
        o.x = rr.x + aa.x; o.y = rr.y + aa.y;
        o.z = rr.z + aa.z; o.w = rr.w + aa.w;
        *(f32x4*)(out + gb + c) = o;
        vals[q * 4 + 0] = o.x; vals[q * 4 + 1] = o.y;
        vals[q * 4 + 2] = o.z; vals[q * 4 + 3] = o.w;
        s1 += o.x + o.y + o.z + o.w;
        s2 += o.x * o.x + o.y * o.y + o.z * o.z + o.w * o.w;
    }
    redu[(tr * 8 + (tid & 7)) * 2 + 0] = s1;
    redu[(tr * 8 + (tid & 7)) * 2 + 1] = s2;
    __syncthreads();                     // redu ready
    float S = 0.f, Q = 0.f;
#pragma unroll
    for (int g2 = 0; g2 < 8; ++g2) {
        S += redu[(tr * 8 + g2) * 2 + 0];
        Q += redu[(tr * 8 + g2) * 2 + 1];
    }
    float mu = S * (1.f / 256.f);
    float var = Q * (1.f / 256.f) - mu * mu;
    float rstd = rsqrtf(var + 1e-5f);
#pragma unroll
    for (int q = 0; q < 8; ++q) {
        int c = c0 + q * 32;
        f32x4 w4 = *(const f32x4*)(n2w + c);
        f32x4 b4 = *(const f32x4*)(n2b + c);
        s16x4 pk;
        pk[0] = (short)f2bf((vals[q * 4 + 0] - mu) * rstd * w4.x + b4.x);
        pk[1] = (short)f2bf((vals[q * 4 + 1] - mu) * rstd * w4.y + b4.y);
        pk[2] = (short)f2bf((vals[q * 4 + 2] - mu) * rstd * w4.z + b4.z);
        pk[3] = (short)f2bf((vals[q * 4 + 3] - mu) * rstd * w4.w + b4.w);
        *(s16x4*)(actA + gb + c) = pk;
    }
}

// MFMA windowed attention: one block per (window, head), 4 waves.
__global__ __launch_bounds__(256) void attn_mfma_kernel(
        const unsigned short* __restrict__ qkv, const float* __restrict__ bm,
        unsigned short* __restrict__ out) {
    __shared__ __attribute__((aligned(16))) unsigned short Vt[32][136];
    __shared__ __attribute__((aligned(16))) unsigned short Pw[4][16][136];
    int blk = blockIdx.x;
    int g = blk >> 3, head = blk & 7;
    int tid = threadIdx.x, wave = tid >> 6, lane = tid & 63;

    for (int i = tid; i < 32 * 30; i += 256) {
        int d = i / 30, c = 98 + (i - d * 30);
        Vt[d][c] = 0;
    }
    const unsigned short* vbase = qkv + (size_t)g * 98 * 768 + 512 + head * 32;
    for (int i = tid; i < 98 * 16; i += 256) {
        int n = i >> 4, dp = i & 15;
        unsigned int val = *(const unsigned int*)(vbase + (size_t)n * 768 + dp * 2);
        Vt[dp * 2][n]     = (unsigned short)val;
        Vt[dp * 2 + 1][n] = (unsigned short)(val >> 16);
    }
    {
        int m = lane >> 2, c = 112 + (lane & 3) * 4;
        *(unsigned long long*)&Pw[wave][m][c] = 0ULL;
    }
    __syncthreads();

    const unsigned short* qbase = qkv + (size_t)g * 98 * 768 + head * 32;
    const unsigned short* kbase = qbase + 256;
    int rem = g & 255;
    int cls = (((rem >> 6) == 3) << 2) | (((((rem >> 3) & 7)) == 7) << 1) | ((rem & 7) == 7);
    const float* bmh = bm + (size_t)(cls * 8 + head) * 112 * 112;

    int fm = lane & 15, fq = lane >> 4;
    int fk = fq * 8;
    unsigned short* obase = out + (size_t)g * 98 * 256 + head * 32;

    for (int s = wave; s < 7; s += 4) {
        int m0 = s * 16;
        int arow = m0 + fm; if (arow > 97) arow = 97;
        short8 af = *(const short8*)(qbase + (size_t)arow * 768 + fk);
        f32x4 S[7];
        f32x4 z = {0.f, 0.f, 0.f, 0.f};
#pragma unroll
        for (int j = 0; j < 7; ++j) {
            int krow = j * 16 + fm; if (krow > 97) krow = 97;
            short8 kf = *(const short8*)(kbase + (size_t)krow * 768 + fk);
            S[j] = __builtin_amdgcn_mfma_f32_16x16x32_bf16(af, kf, z, 0, 0, 0);
        }
        const float* bmrow = bmh + (m0 + fq * 4) * 112 + fm;
#pragma unroll
        for (int j = 0; j < 7; ++j)
#pragma unroll
            for (int v = 0; v < 4; ++v)
                S[j][v] += bmrow[v * 112 + j * 16];
        float inv[4];
#pragma unroll
        for (int v = 0; v < 4; ++v) {
            float m_ = S[0][v];
#pragma unroll
            for (int j = 1; j < 7; ++j) m_ = fmaxf(m_, S[j][v]);
#pragma unroll
            for (int o = 1; o < 16; o <<= 1) m_ = fmaxf(m_, __shfl_xor(m_, o, 64));
            float t = 0.f;
#pragma unroll
            for (int j = 0; j < 7; ++j) { S[j][v] = __expf(S[j][v] - m_); t += S[j][v]; }
#pragma unroll
            for (int o = 1; o < 16; o <<= 1) t += __shfl_xor(t, o, 64);
            inv[v] = 1.f / t;
        }
#pragma unroll
        for (int j = 0; j < 7; ++j)
#pragma unroll
            for (int v = 0; v < 4; ++v)
                Pw[wave][fq * 4 + v][j * 16 + fm] = f2bf(S[j][v]);
        f32x4 O0 = {0.f, 0.f, 0.f, 0.f}, O1 = {0.f, 0.f, 0.f, 0.f};
#pragma unroll
        for (int ks = 0; ks < 4; ++ks) {
            short8 pf = *(const short8*)&Pw[wave][fm][ks * 32 + fk];
            short8 v0 = *(const short8*)&Vt[fm][ks * 32 + fk];
            short8 v1 = *(const short8*)&Vt[16 + fm][ks * 32 + fk];
            O0 = __builtin_amdgcn_mfma_f32_16x16x32_bf16(pf, v0, O0, 0, 0, 0);
            O1 = __builtin_amdgcn_mfma_f32_16x16x32_bf16(pf, v1, O1, 0, 0, 0);
        }
#pragma unroll
        for (int v = 0; v < 4; ++v) {
            int row = m0 + fq * 4 + v;
            if (row < 98) {
                obase[(size_t)row * 256 + fm]      = f2bf(O0[v] * inv[v]);
                obase[(size_t)row * 256 + 16 + fm] = f2bf(O1[v] * inv[v]);
            }
        }
    }
}

extern "C" void kernel_launch(void* const* d_in, const int* in_sizes, int n_in,
                              void* d_out, int out_size, void* d_ws, size_t ws_size,
                              hipStream_t stream) {
    const float* x     = (const float*)d_in[0];
    const float* n1w   = (const float*)d_in[1];
    const float* n1b   = (const float*)d_in[2];
    const float* qkvw  = (const float*)d_in[3];
    const float* qkvb  = (const float*)d_in[4];
    const float* projw = (const float*)d_in[5];
    const float* projb = (const float*)d_in[6];
    const float* rpe   = (const float*)d_in[7];
    const float* n2w   = (const float*)d_in[8];
    const float* n2b   = (const float*)d_in[9];
    const float* fc1w  = (const float*)d_in[10];
    const float* fc1b  = (const float*)d_in[11];
    const float* fc2w  = (const float*)d_in[12];
    const float* fc2b  = (const float*)d_in[13];
    float* out = (float*)d_out;

    // workspace layout
    unsigned short* wqkv  = (unsigned short*)d_ws;            // 768*256 bf16
    unsigned short* wproj = wqkv + 768 * 256;                 // 256*256
    unsigned short* wfc1  = wproj + 256 * 256;                // 1024*256
    unsigned short* wfc2  = wfc1 + 1024 * 256;                // 256*1024
    float* bm = (float*)(wfc2 + 256 * 1024);                  // 8*8*112*112 fp32
    unsigned short* actA  = (unsigned short*)(bm + 8 * 8 * 112 * 112); // TOKENS*256 bf16
    unsigned short* attnO = actA + (size_t)TOKENS * 256;      // TOKENS*256 bf16
    unsigned short* qkv_bf = attnO + (size_t)TOKENS * 256;    // TOKENS*768 bf16
    unsigned short* fc1o = qkv_bf;                            // TOKENS*1024 bf16 (aliases dead qkv)

    // 0. bias/mask tables + weight casts (single fused cast launch)
    bm_kernel<<<8 * 8 * 112 * 112 / 256, 256, 0, stream>>>(rpe, bm);
    cvt_all_kernel<<<786432 / 256, 256, 0, stream>>>(
        qkvw, projw, fc1w, fc2w, wqkv, wproj, wfc1, wfc2);

    // 1. LN1 + roll + window partition (gather), bf16 out
    ln_kernel<true><<<TOKENS / 4, 256, 0, stream>>>(x, n1w, n1b, actA);
    // 2. QKV projection -> bf16, Q pre-scaled
    mfma_gemm<0><<<dim3(768 / 128, TOKENS / 128), 256, 0, stream>>>(
        actA, wqkv, qkvb, qkv_bf, TOKENS, 768, 256);
    // 3. MFMA windowed attention -> bf16
    attn_mfma_kernel<<<NWIN * 8, 256, 0, stream>>>(qkv_bf, bm, attnO);
    // 4. proj + scatter + residual + FUSED LN2 -> out (fp32) + actA (bf16)
    proj_ln_kernel<<<TOKENS / 32, 256, 0, stream>>>(
        attnO, wproj, projb, x, n2w, n2b, out, actA);
    // 5. FC1 + GELU -> bf16, direct stores (aliases dead qkv buffer)
    mfma_gemm<2><<<dim3(1024 / 128, TOKENS / 128), 256, 0, stream>>>(
        actA, wfc1, fc1b, fc1o, TOKENS, 1024, 256);
    // 6. FC2 + residual (in place on d_out), 64x128 tiles, 2-step pipeline
    fc2_kernel<<<dim3(256 / 128, TOKENS / 64), 256, 0, stream>>>(
        fc1o, wfc2, fc2b, out, out, TOKENS, 256, 1024);
}

// Round 13
// 351.501 us; speedup vs baseline: 1.0299x; 1.0252x over previous
//
#include <hip/hip_runtime.h>
#include <math.h>

// Problem constants (fixed by setup_inputs)
#define TOKENS 50176   // B*T*H*W = 2*8*56*56
#define NWIN   512     // total windows = B * 256
#define C_DIM  256

typedef __attribute__((ext_vector_type(8))) short short8;
typedef __attribute__((ext_vector_type(4))) short s16x4;
typedef __attribute__((ext_vector_type(4))) float f32x4;

// float -> bf16 with round-to-nearest-even
__device__ __forceinline__ unsigned short f2bf(float f) {
    unsigned int u = __builtin_bit_cast(unsigned int, f);
    u += 0x7fffu + ((u >> 16) & 1);
    return (unsigned short)(u >> 16);
}

// async global->LDS, 16B per lane (global_load_lds_dwordx4)
__device__ __forceinline__ void gll16(const void* g, void* l) {
    __builtin_amdgcn_global_load_lds(
        (const __attribute__((address_space(1))) unsigned int*)g,
        (__attribute__((address_space(3))) unsigned int*)l, 16, 0, 0);
}

// GELU, Phi-form A&S 7.1.26 (|eps|<=1.5e-7): gelu = v * phi(z),
// phi = (v<0) ? q : 1-q with q = p_half(t) * exp(-z^2); 0.5 folded into
// the poly coefficients. ~13 VALU ops, branch-free.
__device__ __forceinline__ float gelu_exact(float v) {
    float z  = v * 0.70710678118654752f;
    float az = fabsf(z);
    float t  = __builtin_amdgcn_rcpf(1.f + 0.3275911f * az);
    float ph = ((((0.5307027145f * t - 0.7265760135f) * t + 0.7107068705f) * t
                 - 0.142248368f) * t + 0.127414796f) * t;
    float q  = ph * __expf(-az * az);
    float phi = (v < 0.f) ? q : 1.f - q;
    return v * phi;
}

// Map a window-ordered token index u -> flat (b,t,h,w) index.
__device__ __forceinline__ int win_token_to_flat(int u) {
    int g = u / 98;
    int n = u - g * 98;
    int bb  = g >> 8;
    int rem = g & 255;
    int tb = rem >> 6, hb = (rem >> 3) & 7, wb = rem & 7;
    int dt = n / 49;
    int r2 = n - dt * 49;
    int dh = r2 / 7, dw = r2 - dh * 7;
    int t = tb * 2 + dt, h = hb * 7 + dh, w = wb * 7 + dw;
    int ts = (t + 1) & 7;
    int hs = h + 3; if (hs >= 56) hs -= 56;
    int wsx = w + 3; if (wsx >= 56) wsx -= 56;
    return ((bb * 8 + ts) * 56 + hs) * 56 + wsx;
}

// fused elementwise fp32 -> bf16 for all 4 weight matrices (one launch)
__global__ __launch_bounds__(256) void cvt_all_kernel(
        const float* __restrict__ s0, const float* __restrict__ s1,
        const float* __restrict__ s2, const float* __restrict__ s3,
        unsigned short* __restrict__ d0, unsigned short* __restrict__ d1,
        unsigned short* __restrict__ d2, unsigned short* __restrict__ d3) {
    int i = blockIdx.x * 256 + threadIdx.x;       // total 786432 exact
    if (i < 196608)      d0[i] = f2bf(s0[i]);                       // qkv_w
    else if (i < 262144) d1[i - 196608] = f2bf(s1[i - 196608]);     // proj_w
    else if (i < 524288) d2[i - 262144] = f2bf(s2[i - 262144]);     // fc1_w
    else                 d3[i - 524288] = f2bf(s3[i - 524288]);     // fc2_w
}

// Precompute combined rel-pos bias + shift mask tables:
// bm[cls 8][head 8][row 112][col 112] fp32.
__global__ __launch_bounds__(256) void bm_kernel(
        const float* __restrict__ rpe, float* __restrict__ bm) {
    int i = blockIdx.x * 256 + threadIdx.x;   // 8*8*112*112 = 802816 exact
    int c  = i % 112;
    int t1 = i / 112;
    int r  = t1 % 112;
    int t2 = t1 / 112;
    int head = t2 & 7;
    int cls  = t2 >> 3;
    float val;
    if (c >= 98) {
        val = -1e30f;
    } else if (r >= 98) {
        val = 0.f;
    } else {
        int dt = r / 49, rr = r - dt * 49, dh = rr / 7, dw = rr - dh * 7;
        int dt2 = c / 49, cc = c - dt2 * 49, dh2 = cc / 7, dw2 = cc - dh2 * 7;
        int rt  = (cls & 4) ? (dt  == 0 ? 1 : 2) : 0;
        int rh  = (cls & 2) ? (dh  <  4 ? 1 : 2) : 0;
        int rw  = (cls & 1) ? (dw  <  4 ? 1 : 2) : 0;
        int rt2 = (cls & 4) ? (dt2 == 0 ? 1 : 2) : 0;
        int rh2 = (cls & 2) ? (dh2 <  4 ? 1 : 2) : 0;
        int rw2 = (cls & 1) ? (dw2 <  4 ? 1 : 2) : 0;
        int reg1 = rt * 9 + rh * 3 + rw, reg2 = rt2 * 9 + rh2 * 3 + rw2;
        int idx = (dt - dt2 + 1) * 169 + (dh - dh2 + 6) * 13 + (dw - dw2 + 6);
        val = rpe[idx * 8 + head] + ((reg1 == reg2) ? 0.f : -100.f);
    }
    bm[i] = val;
}

// LayerNorm over C=256, one wave per token, bf16 output.
// GATHER: LN1 + roll + window partition fused (gather).
template<bool GATHER>
__global__ __launch_bounds__(256) void ln_kernel(
        const float* __restrict__ x, const float* __restrict__ w,
        const float* __restrict__ b, unsigned short* __restrict__ out) {
    int token = blockIdx.x * 4 + (threadIdx.x >> 6);
    int lane  = threadIdx.x & 63;
    size_t so = GATHER ? (size_t)win_token_to_flat(token) * C_DIM
                       : (size_t)token * C_DIM;
    const float* src = x + so;
    float v[4];
    float sum = 0.f;
#pragma unroll
    for (int j = 0; j < 4; ++j) { v[j] = src[lane + 64 * j]; sum += v[j]; }
#pragma unroll
    for (int o = 32; o > 0; o >>= 1) sum += __shfl_xor(sum, o, 64);
    float mu = sum * (1.f / 256.f);
    float var = 0.f;
#pragma unroll
    for (int j = 0; j < 4; ++j) { float d = v[j] - mu; var += d * d; }
#pragma unroll
    for (int o = 32; o > 0; o >>= 1) var += __shfl_xor(var, o, 64);
    float rstd = rsqrtf(var * (1.f / 256.f) + 1e-5f);
    unsigned short* dst = out + (size_t)token * C_DIM;
#pragma unroll
    for (int j = 0; j < 4; ++j) {
        int c = lane + 64 * j;
        dst[c] = f2bf((v[j] - mu) * rstd * w[c] + b[c]);
    }
}

// bf16 MFMA GEMM (qkv / fc1): C(MxN) = A(MxK) @ B(NxK)^T.
// r2 K-loop (dbuf LDS, one __syncthreads per step), XCD-bijective swizzle.
// EPI 0 (qkv): LDS-staged coalesced epilogue (bf16, *scale on Q cols).
// EPI 2 (fc1): direct fragment-order stores (r11: LDS round-trip made FC1
//   VALU-bound; adjacent j-stores L2-write-combine fine for bf16).
template<int EPI>
__global__ __launch_bounds__(256) void mfma_gemm(
        const unsigned short* __restrict__ A, const unsigned short* __restrict__ B,
        const float* __restrict__ bias,
        void* __restrict__ Cout, int M, int N, int K) {
    __shared__ __attribute__((aligned(16))) unsigned short smem[4][128 * 32]; // 32KB
#define ASMB(b) (smem[(b)])
#define BSMB(b) (smem[2 + (b)])
    int tid = threadIdx.x;
    int wave = tid >> 6, lane = tid & 63;

    int nwg = gridDim.x * gridDim.y;
    int bid = blockIdx.y * gridDim.x + blockIdx.x;
    int swz = (bid & 7) * (nwg >> 3) + (bid >> 3);
    int bx = swz % gridDim.x, by = swz / gridDim.x;

    int row0 = by * 128, col0 = bx * 128;
    int wr = (wave >> 1) * 64;
    int wc = (wave & 1) * 64;

    f32x4 acc[4][4] = {};

    int sr = tid >> 2;
    int sk = (tid & 3) * 8;
    const unsigned short* Ag0 = A + (size_t)(row0 + sr) * K + sk;
    const unsigned short* Ag1 = A + (size_t)(row0 + 64 + sr) * K + sk;
    const unsigned short* Bg0 = B + (size_t)(col0 + sr) * K + sk;
    const unsigned short* Bg1 = B + (size_t)(col0 + 64 + sr) * K + sk;
    int loff = tid * 8;

    int fm = lane & 15, fq = lane >> 4;
    int fks = fq * 8;

    gll16(Ag0, &ASMB(0)[loff]);
    gll16(Ag1, &ASMB(0)[loff + 2048]);
    gll16(Bg0, &BSMB(0)[loff]);
    gll16(Bg1, &BSMB(0)[loff + 2048]);

    int nk = K >> 5;
    for (int s = 0; s < nk; ++s) {
        int cur = s & 1;
        __syncthreads();
        if (s + 1 < nk) {
            int k0 = (s + 1) << 5;
            gll16(Ag0 + k0, &ASMB(cur ^ 1)[loff]);
            gll16(Ag1 + k0, &ASMB(cur ^ 1)[loff + 2048]);
            gll16(Bg0 + k0, &BSMB(cur ^ 1)[loff]);
            gll16(Bg1 + k0, &BSMB(cur ^ 1)[loff + 2048]);
        }
        short8 af[4], bfr[4];
#pragma unroll
        for (int t4 = 0; t4 < 4; ++t4) {
            af[t4]  = *(const short8*)&ASMB(cur)[(wr + t4 * 16 + fm) * 32 + fks];
            bfr[t4] = *(const short8*)&BSMB(cur)[(wc + t4 * 16 + fm) * 32 + fks];
        }
#pragma unroll
        for (int i = 0; i < 4; ++i)
#pragma unroll
            for (int j = 0; j < 4; ++j)
                acc[i][j] = __builtin_amdgcn_mfma_f32_16x16x32_bf16(
                    af[i], bfr[j], acc[i][j], 0, 0, 0);
    }

    int ccol0 = col0 + wc + fm;
    float bj[4];
#pragma unroll
    for (int j = 0; j < 4; ++j) bj[j] = bias[ccol0 + j * 16];

    if (EPI == 2) {
        // FC1: direct fragment-order stores, no LDS round-trip
        unsigned short* C = (unsigned short*)Cout;
        int crow0 = row0 + wr + fq * 4;
#pragma unroll
        for (int i = 0; i < 4; ++i)
#pragma unroll
            for (int v = 0; v < 4; ++v) {
                size_t base = (size_t)(crow0 + i * 16 + v) * N + ccol0;
#pragma unroll
                for (int j = 0; j < 4; ++j)
                    C[base + j * 16] = f2bf(gelu_exact(acc[i][j][v] + bj[j]));
            }
    } else {
        // qkv: LDS-staged coalesced epilogue
        __syncthreads();
        unsigned short* Ls = &smem[0][0];          // [128][128] ushort
        float mul = (col0 < 256) ? 0.17677669529663687f : 1.f;
#pragma unroll
        for (int i = 0; i < 4; ++i)
#pragma unroll
            for (int v = 0; v < 4; ++v) {
                int lr = wr + i * 16 + fq * 4 + v;
#pragma unroll
                for (int j = 0; j < 4; ++j)
                    Ls[lr * 128 + wc + j * 16 + fm] = f2bf((acc[i][j][v] + bj[j]) * mul);
            }
        __syncthreads();
        unsigned short* C = (unsigned short*)Cout;
#pragma unroll
        for (int p = 0; p < 8; ++p) {
            int lin = p * 2048 + tid * 8;
            int lr = lin >> 7, lc = lin & 127;
            *(short8*)(C + (size_t)(row0 + lr) * N + col0 + lc) =
                *(const short8*)&Ls[lin];
        }
    }
#undef ASMB
#undef BSMB
}

// ---------------------------------------------------------------------------
// FC2 GEMM, 64x128 tile, r12: 2 K-steps per barrier, 4 LDS buffers (48KB).
// Loads drained at barrier i were issued one iteration = TWO K-steps earlier;
// barrier count halves. Confirmed win (fc2 59.5 -> <58.8, left top-5).
// out = res + A@B^T + bias (fp32, in place: res == out).
// ---------------------------------------------------------------------------
__global__ __launch_bounds__(256) void fc2_kernel(
        const unsigned short* __restrict__ A, const unsigned short* __restrict__ B,
        const float* __restrict__ bias, const float* __restrict__ res,
        float* __restrict__ Cout, int M, int N, int K) {
    // ushort layout: A bufs [4][2048] @0 (4KB each); B bufs [4][4096] @8192
    __shared__ __attribute__((aligned(16))) unsigned short L[24576];  // 48KB
    int tid = threadIdx.x;
    int wave = tid >> 6, lane = tid & 63;
    int fm = lane & 15, fq = lane >> 4;

    int nwg = gridDim.x * gridDim.y;     // 1568
    int bid = blockIdx.y * gridDim.x + blockIdx.x;
    int swz = (bid & 7) * (nwg >> 3) + (bid >> 3);
    int bx = swz % gridDim.x, by = swz / gridDim.x;

    int row0 = by * 64, col0 = bx * 128;
    int wrow = (wave >> 1) * 32;
    int wcol = (wave & 1) * 64;

    f32x4 acc[2][4] = {};

    int sr = tid >> 2, sk = (tid & 3) * 8;
    const unsigned short* Ag  = A + (size_t)(row0 + sr) * K + sk;
    const unsigned short* Bg0 = B + (size_t)(col0 + sr) * K + sk;
    const unsigned short* Bg1 = B + (size_t)(col0 + 64 + sr) * K + sk;
    int loff = tid * 8;

    // stage K-step s into buf s&3
#define STAGE(s)  do { int _k = (s) << 5; int _b = (s) & 3;                    \
        gll16(Ag  + _k, &L[_b * 2048 + loff]);                                 \
        gll16(Bg0 + _k, &L[8192 + _b * 4096 + loff]);                          \
        gll16(Bg1 + _k, &L[8192 + _b * 4096 + 2048 + loff]); } while (0)

    // prologue: steps 0,1 in flight
    STAGE(0);
    STAGE(1);

    int nk = K >> 5;                     // 32 (even)
    for (int i = 0; i < nk; i += 2) {
        __syncthreads();                 // steps i,i+1 staged; bufs (i+2)&3,(i+3)&3 sealed
        if (i + 2 < nk) { STAGE(i + 2); STAGE(i + 3); }
#pragma unroll
        for (int u = 0; u < 2; ++u) {
            int b = (i + u) & 3;
            short8 af[2], bfr[4];
#pragma unroll
            for (int r = 0; r < 2; ++r)
                af[r] = *(const short8*)&L[b * 2048 + (wrow + r * 16 + fm) * 32 + fq * 8];
#pragma unroll
            for (int j = 0; j < 4; ++j)
                bfr[j] = *(const short8*)&L[8192 + b * 4096 +
                                            (wcol + j * 16 + fm) * 32 + fq * 8];
#pragma unroll
            for (int r = 0; r < 2; ++r)
#pragma unroll
                for (int j = 0; j < 4; ++j)
                    acc[r][j] = __builtin_amdgcn_mfma_f32_16x16x32_bf16(
                        af[r], bfr[j], acc[r][j], 0, 0, 0);
        }
    }
#undef STAGE

    float bj[4];
#pragma unroll
    for (int j = 0; j < 4; ++j) bj[j] = bias[col0 + wcol + j * 16 + fm];

    __syncthreads();                     // K-loop LDS reads done; reuse L

    float* fs = (float*)L;               // [32][128] fp32 = 16KB
#pragma unroll
    for (int h = 0; h < 2; ++h) {
        if (h) __syncthreads();
        if ((wave >> 1) == h) {
#pragma unroll
            for (int r = 0; r < 2; ++r)
#pragma unroll
                for (int v = 0; v < 4; ++v) {
                    int lr = r * 16 + fq * 4 + v;
#pragma unroll
                    for (int j = 0; j < 4; ++j)
                        fs[lr * 128 + wcol + j * 16 + fm] = acc[r][j][v] + bj[j];
                }
        }
        __syncthreads();
        int tr = tid >> 3, c0 = (tid & 7) * 4;
        size_t gbase = (size_t)(row0 + h * 32 + tr) * N + col0;
        const float* rs = res + gbase;
        float* Cp = Cout + gbase;
        const float* ls = &fs[tr * 128];
#pragma unroll
        for (int q = 0; q < 4; ++q) {
            int c = c0 + q * 32;
            f32x4 r = *(const f32x4*)(rs + c);
            f32x4 a = *(const f32x4*)(ls + c);
            r.x += a.x; r.y += a.y; r.z += a.z; r.w += a.w;
            *(f32x4*)(Cp + c) = r;
        }
    }
}

// ---------------------------------------------------------------------------
// proj + window-reverse/roll scatter + residual + FUSED LayerNorm2.
// 32x256 tile, grid 1568; single-pass epilogue. Block owns full rows ->
// LN block-local. LDS 36KB.
// ---------------------------------------------------------------------------
__global__ __launch_bounds__(256) void proj_ln_kernel(
        const unsigned short* __restrict__ A,    // attnO (window order) bf16
        const unsigned short* __restrict__ B,    // wproj [256][256] bf16
        const float* __restrict__ bias,          // projb
        const float* __restrict__ res,           // x (flat order) fp32
        const float* __restrict__ n2w, const float* __restrict__ n2b,
        float* __restrict__ out,                 // x1 fp32 (flat)
        unsigned short* __restrict__ actA) {     // LN2(out) bf16 (flat)
    // ushort layout: A dbuf [2][32*32=1024] @0; B dbuf [2][256*32=8192] @2048
    __shared__ __attribute__((aligned(16))) unsigned short L[18432];  // 36KB
    int tid = threadIdx.x;
    int wave = tid >> 6, lane = tid & 63;
    int fm = lane & 15, fq = lane >> 4;

    int nwg = gridDim.x;                 // 1568
    int bid = blockIdx.x;
    int swz = (bid & 7) * (nwg >> 3) + (bid >> 3);
    int r0 = swz * 32;

    int wrow = (wave >> 1) * 16;         // 0 or 16
    int wcol = (wave & 1) * 128;         // 0 or 128

    f32x4 acc[8] = {};

    int sr = tid >> 2, sk = (tid & 3) * 8;
    const unsigned short* Ag = A + (size_t)(r0 + sr) * 256 + sk;
    const unsigned short* Bg = B + (size_t)sr * 256 + sk;

    if (tid < 128) gll16(Ag, &L[tid * 8]);
#pragma unroll
    for (int p = 0; p < 4; ++p)
        gll16(Bg + (size_t)p * 64 * 256, &L[2048 + p * 2048 + tid * 8]);

    for (int s = 0; s < 8; ++s) {
        int cur = s & 1;
        __syncthreads();
        if (s + 1 < 8) {
            int k0 = (s + 1) << 5;
            if (tid < 128) gll16(Ag + k0, &L[(cur ^ 1) * 1024 + tid * 8]);
#pragma unroll
            for (int p = 0; p < 4; ++p)
                gll16(Bg + (size_t)p * 64 * 256 + k0,
                      &L[2048 + (cur ^ 1) * 8192 + p * 2048 + tid * 8]);
        }
        short8 af = *(const short8*)&L[cur * 1024 + (wrow + fm) * 32 + fq * 8];
        short8 bfr[8];
#pragma unroll
        for (int j = 0; j < 8; ++j)
            bfr[j] = *(const short8*)&L[2048 + cur * 8192 +
                                        (wcol + j * 16 + fm) * 32 + fq * 8];
#pragma unroll
        for (int j = 0; j < 8; ++j)
            acc[j] = __builtin_amdgcn_mfma_f32_16x16x32_bf16(
                af, bfr[j], acc[j], 0, 0, 0);
    }

    float bj[8];
#pragma unroll
    for (int j = 0; j < 8; ++j) bj[j] = bias[wcol + j * 16 + fm];

    __syncthreads();                     // K-loop LDS reads done; reuse L

    float* fs   = (float*)L;             // [32][260] fp32 (stride-pad 4)
    float* redu = (float*)&L[16640];     // [32][8][2] fp32 (2KB)

#pragma unroll
    for (int v = 0; v < 4; ++v) {
        int lr = wrow + fq * 4 + v;
#pragma unroll
        for (int j = 0; j < 8; ++j)
            fs[lr * 260 + wcol + j * 16 + fm] = acc[j][v] + bj[j];
    }
    __syncthreads();                     // fs ready
    int tr = tid >> 3;                   // row 0..31
    int c0 = (tid & 7) * 4;              // interleaved float4 chunks
    int flat = win_token_to_flat(r0 + tr);
    size_t gb = (size_t)flat * 256;
    float vals[32];
    float s1 = 0.f, s2 = 0.f;
#pragma unroll
    for (int q = 0; q < 8; ++q) {
        int c = c0 + q * 32;
        f32x4 rr = *(const f32x4*)(res + gb + c);
        f32x4 aa = *(const f32x4*)&fs[tr * 260 + c];
        f32x4 o;
        o.x = rr.x + aa.x; o.y = rr.y + aa.y;
        o.z = rr.z + aa.z; o.w = rr.w + aa.w;
        *(f32x4*)(out + gb + c) = o;
        vals[q * 4 + 0] = o.x; vals[q * 4 + 1] = o.y;
        vals[q * 4 + 2] = o.z; vals[q * 4 + 3] = o.w;
        s1 += o.x + o.y + o.z + o.w;
        s2 += o.x * o.x + o.y * o.y + o.z * o.z + o.w * o.w;
    }
    redu[(tr * 8 + (tid & 7)) * 2 + 0] = s1;
    redu[(tr * 8 + (tid & 7)) * 2 + 1] = s2;
    __syncthreads();                     // redu ready
    float S = 0.f, Q = 0.f;
#pragma unroll
    for (int g2 = 0; g2 < 8; ++g2) {
        S += redu[(tr * 8 + g2) * 2 + 0];
        Q += redu[(tr * 8 + g2) * 2 + 1];
    }
    float mu = S * (1.f / 256.f);
    float var = Q * (1.f / 256.f) - mu * mu;
    float rstd = rsqrtf(var + 1e-5f);
#pragma unroll
    for (int q = 0; q < 8; ++q) {
        int c = c0 + q * 32;
        f32x4 w4 = *(const f32x4*)(n2w + c);
        f32x4 b4 = *(const f32x4*)(n2b + c);
        s16x4 pk;
        pk[0] = (short)f2bf((vals[q * 4 + 0] - mu) * rstd * w4.x + b4.x);
        pk[1] = (short)f2bf((vals[q * 4 + 1] - mu) * rstd * w4.y + b4.y);
        pk[2] = (short)f2bf((vals[q * 4 + 2] - mu) * rstd * w4.z + b4.z);
        pk[3] = (short)f2bf((vals[q * 4 + 3] - mu) * rstd * w4.w + b4.w);
        *(s16x4*)(actA + gb + c) = pk;
    }
}

// ---------------------------------------------------------------------------
// MFMA windowed attention, r13: one block per (window, head), 7 WAVES (448
// threads) — exactly ONE 16-row strip per wave. The r12 counters showed the
// 4-wave/7-strip split (waves 0-2: 2 strips, wave 3: 1) leaves >=1 wave idle
// for the entire second strip pass; all pipes <40% while dur stays 59us.
// LDS: Vt 8.5KB + Pw[7] 30.5KB = 38.3KB -> 4 blocks/CU = 28 waves/CU.
// ---------------------------------------------------------------------------
__global__ __launch_bounds__(448) void attn_mfma_kernel(
        const unsigned short* __restrict__ qkv, const float* __restrict__ bm,
        unsigned short* __restrict__ out) {
    __shared__ __attribute__((aligned(16))) unsigned short Vt[32][136];
    __shared__ __attribute__((aligned(16))) unsigned short Pw[7][16][136];
    int blk = blockIdx.x;
    int g = blk >> 3, head = blk & 7;
    int tid = threadIdx.x, wave = tid >> 6, lane = tid & 63;

    // zero Vt token-pad cols [98,128)
    for (int i = tid; i < 32 * 30; i += 448) {
        int d = i / 30, c = 98 + (i - d * 30);
        Vt[d][c] = 0;
    }
    // stage V_h transposed: Vt[d][token], coalesced global reads
    const unsigned short* vbase = qkv + (size_t)g * 98 * 768 + 512 + head * 32;
    for (int i = tid; i < 98 * 16; i += 448) {
        int n = i >> 4, dp = i & 15;
        unsigned int val = *(const unsigned int*)(vbase + (size_t)n * 768 + dp * 2);
        Vt[dp * 2][n]     = (unsigned short)val;
        Vt[dp * 2 + 1][n] = (unsigned short)(val >> 16);
    }
    // zero per-wave P k-pad cols [112,128)
    {
        int m = lane >> 2, c = 112 + (lane & 3) * 4;
        *(unsigned long long*)&Pw[wave][m][c] = 0ULL;
    }
    __syncthreads();

    const unsigned short* qbase = qkv + (size_t)g * 98 * 768 + head * 32;
    const unsigned short* kbase = qbase + 256;
    int rem = g & 255;
    int cls = (((rem >> 6) == 3) << 2) | (((((rem >> 3) & 7)) == 7) << 1) | ((rem & 7) == 7);
    const float* bmh = bm + (size_t)(cls * 8 + head) * 112 * 112;

    int fm = lane & 15, fq = lane >> 4;
    int fk = fq * 8;
    unsigned short* obase = out + (size_t)g * 98 * 256 + head * 32;

    {   // one strip per wave: s = wave in [0,7)
        int s = wave;
        int m0 = s * 16;
        int arow = m0 + fm; if (arow > 97) arow = 97;   // clamp pad rows
        short8 af = *(const short8*)(qbase + (size_t)arow * 768 + fk);
        f32x4 S[7];
        f32x4 z = {0.f, 0.f, 0.f, 0.f};
#pragma unroll
        for (int j = 0; j < 7; ++j) {
            int krow = j * 16 + fm; if (krow > 97) krow = 97;
            short8 kf = *(const short8*)(kbase + (size_t)krow * 768 + fk);
            S[j] = __builtin_amdgcn_mfma_f32_16x16x32_bf16(af, kf, z, 0, 0, 0);
        }
        const float* bmrow = bmh + (m0 + fq * 4) * 112 + fm;
#pragma unroll
        for (int j = 0; j < 7; ++j)
#pragma unroll
            for (int v = 0; v < 4; ++v)
                S[j][v] += bmrow[v * 112 + j * 16];
        float inv[4];
#pragma unroll
        for (int v = 0; v < 4; ++v) {
            float m_ = S[0][v];
#pragma unroll
            for (int j = 1; j < 7; ++j) m_ = fmaxf(m_, S[j][v]);
#pragma unroll
            for (int o = 1; o < 16; o <<= 1) m_ = fmaxf(m_, __shfl_xor(m_, o, 64));
            float t = 0.f;
#pragma unroll
            for (int j = 0; j < 7; ++j) { S[j][v] = __expf(S[j][v] - m_); t += S[j][v]; }
#pragma unroll
            for (int o = 1; o < 16; o <<= 1) t += __shfl_xor(t, o, 64);
            inv[v] = 1.f / t;
        }
        // P: C-layout -> A-layout via per-wave LDS (same-wave DS ordering)
#pragma unroll
        for (int j = 0; j < 7; ++j)
#pragma unroll
            for (int v = 0; v < 4; ++v)
                Pw[wave][fq * 4 + v][j * 16 + fm] = f2bf(S[j][v]);
        // O = P @ V
        f32x4 O0 = {0.f, 0.f, 0.f, 0.f}, O1 = {0.f, 0.f, 0.f, 0.f};
#pragma unroll
        for (int ks = 0; ks < 4; ++ks) {
            short8 pf = *(const short8*)&Pw[wave][fm][ks * 32 + fk];
            short8 v0 = *(const short8*)&Vt[fm][ks * 32 + fk];
            short8 v1 = *(const short8*)&Vt[16 + fm][ks * 32 + fk];
            O0 = __builtin_amdgcn_mfma_f32_16x16x32_bf16(pf, v0, O0, 0, 0, 0);
            O1 = __builtin_amdgcn_mfma_f32_16x16x32_bf16(pf, v1, O1, 0, 0, 0);
        }
#pragma unroll
        for (int v = 0; v < 4; ++v) {
            int row = m0 + fq * 4 + v;
            if (row < 98) {
                obase[(size_t)row * 256 + fm]      = f2bf(O0[v] * inv[v]);
                obase[(size_t)row * 256 + 16 + fm] = f2bf(O1[v] * inv[v]);
            }
        }
    }
}

extern "C" void kernel_launch(void* const* d_in, const int* in_sizes, int n_in,
                              void* d_out, int out_size, void* d_ws, size_t ws_size,
                              hipStream_t stream) {
    const float* x     = (const float*)d_in[0];
    const float* n1w   = (const float*)d_in[1];
    const float* n1b   = (const float*)d_in[2];
    const float* qkvw  = (const float*)d_in[3];
    const float* qkvb  = (const float*)d_in[4];
    const float* projw = (const float*)d_in[5];
    const float* projb = (const float*)d_in[6];
    const float* rpe   = (const float*)d_in[7];
    const float* n2w   = (const float*)d_in[8];
    const float* n2b   = (const float*)d_in[9];
    const float* fc1w  = (const float*)d_in[10];
    const float* fc1b  = (const float*)d_in[11];
    const float* fc2w  = (const float*)d_in[12];
    const float* fc2b  = (const float*)d_in[13];
    float* out = (float*)d_out;

    // workspace layout
    unsigned short* wqkv  = (unsigned short*)d_ws;            // 768*256 bf16
    unsigned short* wproj = wqkv + 768 * 256;                 // 256*256
    unsigned short* wfc1  = wproj + 256 * 256;                // 1024*256
    unsigned short* wfc2  = wfc1 + 1024 * 256;                // 256*1024
    float* bm = (float*)(wfc2 + 256 * 1024);                  // 8*8*112*112 fp32
    unsigned short* actA  = (unsigned short*)(bm + 8 * 8 * 112 * 112); // TOKENS*256 bf16
    unsigned short* attnO = actA + (size_t)TOKENS * 256;      // TOKENS*256 bf16
    unsigned short* qkv_bf = attnO + (size_t)TOKENS * 256;    // TOKENS*768 bf16
    unsigned short* fc1o = qkv_bf;                            // TOKENS*1024 bf16 (aliases dead qkv)

    // 0. bias/mask tables + weight casts (single fused cast launch)
    bm_kernel<<<8 * 8 * 112 * 112 / 256, 256, 0, stream>>>(rpe, bm);
    cvt_all_kernel<<<786432 / 256, 256, 0, stream>>>(
        qkvw, projw, fc1w, fc2w, wqkv, wproj, wfc1, wfc2);

    // 1. LN1 + roll + window partition (gather), bf16 out
    ln_kernel<true><<<TOKENS / 4, 256, 0, stream>>>(x, n1w, n1b, actA);
    // 2. QKV projection -> bf16, Q pre-scaled
    mfma_gemm<0><<<dim3(768 / 128, TOKENS / 128), 256, 0, stream>>>(
        actA, wqkv, qkvb, qkv_bf, TOKENS, 768, 256);
    // 3. MFMA windowed attention -> bf16 (7 waves, 1 strip/wave)
    attn_mfma_kernel<<<NWIN * 8, 448, 0, stream>>>(qkv_bf, bm, attnO);
    // 4. proj + scatter + residual + FUSED LN2 -> out (fp32) + actA (bf16)
    proj_ln_kernel<<<TOKENS / 32, 256, 0, stream>>>(
        attnO, wproj, projb, x, n2w, n2b, out, actA);
    // 5. FC1 + GELU -> bf16, direct stores (aliases dead qkv buffer)
    mfma_gemm<2><<<dim3(1024 / 128, TOKENS / 128), 256, 0, stream>>>(
        actA, wfc1, fc1b, fc1o, TOKENS, 1024, 256);
    // 6. FC2 + residual (in place on d_out), 64x128 tiles, 2-step pipeline
    fc2_kernel<<<dim3(256 / 128, TOKENS / 64), 256, 0, stream>>>(
        fc1o, wfc2, fc2b, out, out, TOKENS, 256, 1024);
}